// Round 7
// baseline (193.534 us; speedup 1.0000x reference)
//
#include <hip/hip_runtime.h>
#include <cstddef>

// ---------------------------------------------------------------------------
// MultiHead attention, B=4 T=1024 D=1024 N=16 DH=64, SCALE=32, causal + bias.
// Round 7: attn pipelined — KVBLK=32, ring-4 LDS buffers, counted vmcnt(8)
// (never drain to 0 mid-loop), raw s_barrier. 3 compute-phases of slack per
// staged tile ≈ HBM latency. Mask staged once to LDS. proj/out unchanged.
// ---------------------------------------------------------------------------

typedef __attribute__((ext_vector_type(8))) short bf16x8;
typedef __attribute__((ext_vector_type(4))) float f32x4;

#define MFMA16(a, b, c) __builtin_amdgcn_mfma_f32_16x16x32_bf16(a, b, c, 0, 0, 0)

__device__ __forceinline__ short f2bf(float f) {
  union { float f; unsigned int i; } v; v.f = f;
  unsigned int r = v.i + 0x7FFFu + ((v.i >> 16) & 1u);  // RNE
  return (short)(r >> 16);
}

__device__ __forceinline__ void gload_lds16(const void* g, void* l) {
  __builtin_amdgcn_global_load_lds(
      (const __attribute__((address_space(1))) void*)g,
      (__attribute__((address_space(3))) void*)l, 16, 0, 0);
}

// ---------------------------------------------------------------------------
// Fused f32 -> bf16 conversion for all 7 tensors (one launch).
// ---------------------------------------------------------------------------
__global__ __launch_bounds__(256) void cvt_all(
    const float* __restrict__ q, const float* __restrict__ k, const float* __restrict__ v,
    const float* __restrict__ wq, const float* __restrict__ wk,
    const float* __restrict__ wv, const float* __restrict__ wo,
    short* __restrict__ qb, short* __restrict__ kb, short* __restrict__ vb,
    short* __restrict__ wqb, short* __restrict__ wkb,
    short* __restrict__ wvb, short* __restrict__ wob) {
  const int total = 16 * 1048576 / 4;  // vec4 count
  int stride = gridDim.x * blockDim.x;
  for (int i = blockIdx.x * blockDim.x + threadIdx.x; i < total; i += stride) {
    int e = i * 4;
    int chunk = e >> 20;
    const float* s;
    short* d;
    int off;
    if (chunk < 12) {
      if (chunk < 4)      { s = q; d = qb; }
      else if (chunk < 8) { s = k; d = kb; }
      else                { s = v; d = vb; }
      off = e & (4 * 1048576 - 1);
    } else {
      int w = chunk - 12;
      if (w == 0)      { s = wq; d = wqb; }
      else if (w == 1) { s = wk; d = wkb; }
      else if (w == 2) { s = wv; d = wvb; }
      else             { s = wo; d = wob; }
      off = e & (1048576 - 1);
    }
    float4 x = *(const float4*)(s + off);
    short4 o;
    o.x = f2bf(x.x); o.y = f2bf(x.y); o.z = f2bf(x.z); o.w = f2bf(x.w);
    *(short4*)(d + off) = o;
  }
}

// ---------------------------------------------------------------------------
// Fused Q/K/V projection: 256x64 tile, 4 waves stacked, BK=64 (round 3).
// ---------------------------------------------------------------------------
__global__ __launch_bounds__(256) void proj_qkv(
    const short* __restrict__ qA, const short* __restrict__ kA, const short* __restrict__ vA,
    const short* __restrict__ Wqb, const short* __restrict__ Wkb, const short* __restrict__ Wvb,
    const float* __restrict__ bq, const float* __restrict__ bk, const float* __restrict__ bv,
    short* __restrict__ Qh, short* __restrict__ Kh, short* __restrict__ Vth) {
  __shared__ short SMEM[256 * 64 + 64 * 64];  // As(32K) + Bs(8K); reused as Vt
  short* As = SMEM;
  short* Bs = SMEM + 256 * 64;

  const int m0 = blockIdx.x * 256;
  const int n0 = blockIdx.y * 64;
  const int z = blockIdx.z;

  const short *A, *W;
  const float* bias;
  if (z == 0)      { A = qA; W = Wqb; bias = bq; }
  else if (z == 1) { A = kA; W = Wkb; bias = bk; }
  else             { A = vA; W = Wvb; bias = bv; }

  const int tid = threadIdx.x;
  const int wid = tid >> 6, lane = tid & 63;
  const int fr = lane & 15, fq = lane >> 4;

  f32x4 acc[4][4] = {};

  for (int kt = 0; kt < 16; ++kt) {
#pragma unroll
    for (int c = 0; c < 8; ++c) {
      int pbase = c * 4096 + wid * 1024;
      int pb = pbase + lane * 16;
      int lb = pb ^ (((pb >> 7) & 7) << 4);
      int grow = lb >> 7, gcol = (lb & 127) >> 1;
      gload_lds16(A + (size_t)(m0 + grow) * 1024 + kt * 64 + gcol, (char*)As + pbase);
    }
#pragma unroll
    for (int c = 0; c < 2; ++c) {
      int pbase = c * 4096 + wid * 1024;
      int pb = pbase + lane * 16;
      int lb = pb ^ (((pb >> 7) & 7) << 4);
      int grow = lb >> 7, gcol = (lb & 127) >> 1;
      gload_lds16(W + (size_t)(n0 + grow) * 1024 + kt * 64 + gcol, (char*)Bs + pbase);
    }
    __syncthreads();
#pragma unroll
    for (int kk = 0; kk < 2; ++kk) {
      bf16x8 af[4], bg[4];
      int cb = (fq * 8 + kk * 32) * 2;
#pragma unroll
      for (int m = 0; m < 4; ++m) {
        int r = wid * 64 + m * 16 + fr;
        af[m] = *(const bf16x8*)((const char*)As + (((r << 7) + cb) ^ ((r & 7) << 4)));
      }
#pragma unroll
      for (int n = 0; n < 4; ++n) {
        int r = n * 16 + fr;
        bg[n] = *(const bf16x8*)((const char*)Bs + (((r << 7) + cb) ^ ((r & 7) << 4)));
      }
#pragma unroll
      for (int m = 0; m < 4; ++m)
#pragma unroll
        for (int n = 0; n < 4; ++n)
          acc[m][n] = MFMA16(af[m], bg[n], acc[m][n]);
    }
    __syncthreads();
  }

  if (z < 2) {
    short* dst = (z == 0) ? Qh : Kh;
#pragma unroll
    for (int m = 0; m < 4; ++m)
#pragma unroll
      for (int n = 0; n < 4; ++n) {
        int col = n0 + n * 16 + fr;
        float bval = bias[col];
        int row0 = m0 + wid * 64 + m * 16 + fq * 4;
        int hh = col >> 6, dh = col & 63;
#pragma unroll
        for (int j = 0; j < 4; ++j) {
          int row = row0 + j;
          int bb = row >> 10, t = row & 1023;
          dst[(((size_t)(bb * 16 + hh)) * 1024 + t) * 64 + dh] = f2bf(acc[m][n][j] + bval);
        }
      }
  } else {
    short* Vt = SMEM;  // [64][264] shorts
#pragma unroll
    for (int m = 0; m < 4; ++m)
#pragma unroll
      for (int n = 0; n < 4; ++n) {
        int coll = n * 16 + fr;
        float bval = bias[n0 + coll];
        int rowl0 = wid * 64 + m * 16 + fq * 4;
#pragma unroll
        for (int j = 0; j < 4; ++j)
          Vt[coll * 264 + rowl0 + j] = f2bf(acc[m][n][j] + bval);
      }
    __syncthreads();
    const int bb = m0 >> 10, t0 = m0 & 1023;
#pragma unroll
    for (int it = 0; it < 8; ++it) {
      int qq = tid + it * 256;
      int rowl = qq >> 5, seg = qq & 31;
      bf16x8 vv = *(const bf16x8*)&Vt[rowl * 264 + seg * 8];
      int cg = n0 + rowl, hh = cg >> 6, dh = cg & 63;
      *(bf16x8*)&Vth[(((size_t)(bb * 16 + hh)) * 64 + dh) * 1024 + t0 + seg * 8] = vv;
    }
  }
}

// ---------------------------------------------------------------------------
// Output projection: 512 thr / 8 waves, 256x64 tile (round 3).
// ---------------------------------------------------------------------------
__global__ __launch_bounds__(512) void gemm_out(const short* __restrict__ A,
                                                const short* __restrict__ W,
                                                const float* __restrict__ bias,
                                                float* __restrict__ C) {
  __shared__ short As[256 * 64];
  __shared__ short Bs[64 * 64];
  const int m0 = blockIdx.x * 256;
  const int n0 = blockIdx.y * 64;

  const int tid = threadIdx.x;
  const int wid = tid >> 6, lane = tid & 63;
  const int fr = lane & 15, fq = lane >> 4;

  f32x4 acc[2][4] = {};

  for (int kt = 0; kt < 16; ++kt) {
#pragma unroll
    for (int c = 0; c < 4; ++c) {
      int pbase = c * 8192 + wid * 1024;
      int pb = pbase + lane * 16;
      int lb = pb ^ (((pb >> 7) & 7) << 4);
      int grow = lb >> 7, gcol = (lb & 127) >> 1;
      gload_lds16(A + (size_t)(m0 + grow) * 1024 + kt * 64 + gcol, (char*)As + pbase);
    }
    {
      int pbase = wid * 1024;
      int pb = pbase + lane * 16;
      int lb = pb ^ (((pb >> 7) & 7) << 4);
      int grow = lb >> 7, gcol = (lb & 127) >> 1;
      gload_lds16(W + (size_t)(n0 + grow) * 1024 + kt * 64 + gcol, (char*)Bs + pbase);
    }
    __syncthreads();
#pragma unroll
    for (int kk = 0; kk < 2; ++kk) {
      bf16x8 af[2], bg[4];
      int cb = (fq * 8 + kk * 32) * 2;
#pragma unroll
      for (int m = 0; m < 2; ++m) {
        int r = wid * 32 + m * 16 + fr;
        af[m] = *(const bf16x8*)((const char*)As + (((r << 7) + cb) ^ ((r & 7) << 4)));
      }
#pragma unroll
      for (int n = 0; n < 4; ++n) {
        int r = n * 16 + fr;
        bg[n] = *(const bf16x8*)((const char*)Bs + (((r << 7) + cb) ^ ((r & 7) << 4)));
      }
#pragma unroll
      for (int m = 0; m < 2; ++m)
#pragma unroll
        for (int n = 0; n < 4; ++n)
          acc[m][n] = MFMA16(af[m], bg[n], acc[m][n]);
    }
    __syncthreads();
  }

#pragma unroll
  for (int m = 0; m < 2; ++m)
#pragma unroll
    for (int n = 0; n < 4; ++n) {
      int col = n0 + n * 16 + fr;
      float bval = bias[col];
      int row0 = m0 + wid * 32 + m * 16 + fq * 4;
#pragma unroll
      for (int j = 0; j < 4; ++j)
        C[(size_t)(row0 + j) * 1024 + col] = acc[m][n][j] + bval;
    }
}

// ---------------------------------------------------------------------------
// Flash attention: grid (16 q-tiles, 64 heads), 256 thr (4 waves), QBLK=64.
// KVBLK=32, RING-4 buffers, counted vmcnt: stage(kt+3) at iter top; at iter
// end wait vmcnt(8/4/0) (= loads of tiles younger than kt+1 stay in flight),
// then raw s_barrier. Swapped QK^T (lane owns one q-row). Mask staged once.
// ---------------------------------------------------------------------------
__global__ __launch_bounds__(256) void attn_kernel(
    const short* __restrict__ Qh, const short* __restrict__ Kh,
    const short* __restrict__ Vth, const float* __restrict__ Wb,
    const float* __restrict__ mask, short* __restrict__ Aout) {
  __shared__ short Ks[4][2048];   // [k 0..31][dh 0..63], 128B rows, ^((r&7)<<4)
  __shared__ short Vs[4][2048];   // [dh 0..63][k 0..31], 64B rows, ^(((r^(r>>2))&3)<<4)
  __shared__ float Bi[4][2048];   // [q 0..63][k 0..31] f32, 128B rows, ^((r&7)<<4)
  __shared__ float Ms[1024];      // mask row for this batch
  __shared__ short Ps[4][640];    // per-wave P [16 q][32 k], stride 40 shorts

  const int tid = threadIdx.x;
  const int wid = tid >> 6, lane = tid & 63;
  const int fr = lane & 15, fq = lane >> 4;
  const int h = blockIdx.y, b = h >> 4;
  const int qi = (int)gridDim.x - 1 - (int)blockIdx.x;  // heavy tiles first
  const int q0 = qi * 64;
  const int NT = 2 * qi + 2;            // 32-wide KV tiles (covers k < q0+64)

  // Q fragment (B-operand): Q[q = qrow][dh = fq*8 + {0..7}] (+32 for kk=1)
  const int qrow = q0 + wid * 16 + fr;  // this lane's q-row
  const short* qbase = Qh + ((size_t)h * 1024 + qrow) * 64 + fq * 8;
  bf16x8 qf0 = *(const bf16x8*)qbase;
  bf16x8 qf1 = *(const bf16x8*)(qbase + 32);

  const short* Kbase = Kh + (size_t)h * 1024 * 64;
  const short* Vbase = Vth + (size_t)h * 64 * 1024;
  const float* wbase = Wb + (size_t)h * 1024 * 1024;
  const float* mbase = mask + b * 1024;

  // stage one 32-k tile into ring slot buf: K 1 + V 1 + bias 2 gloads per wave
  auto stage = [&](int buf, int kt2) {
    const int k0 = kt2 * 32;
    {  // K tile: 4 KB
      int pb = wid * 1024 + lane * 16;
      int lb = pb ^ (((pb >> 7) & 7) << 4);
      gload_lds16(Kbase + (size_t)(k0 + (lb >> 7)) * 64 + ((lb & 127) >> 1),
                  (char*)Ks[buf] + wid * 1024);
    }
    {  // V^T tile: 4 KB, 64B rows
      int pb = wid * 1024 + lane * 16;
      int lb = pb ^ ((((pb >> 6) ^ (pb >> 8)) & 3) << 4);
      gload_lds16(Vbase + (size_t)(lb >> 6) * 1024 + k0 + ((lb & 63) >> 1),
                  (char*)Vs[buf] + wid * 1024);
    }
#pragma unroll
    for (int c = 0; c < 2; ++c) {  // bias tile: 8 KB
      int pbase = c * 4096 + wid * 1024;
      int pb = pbase + lane * 16;
      int lb = pb ^ (((pb >> 7) & 7) << 4);
      gload_lds16(wbase + (size_t)(q0 + (lb >> 7)) * 1024 + k0 + ((lb & 127) >> 2),
                  (char*)Bi[buf] + pbase);
    }
  };

  f32x4 o_acc[4] = {};
  float m_run = -3.0e38f, l_run = 0.f;

  // ---- prologue: mask + first min(3,NT) tiles ----
  gload_lds16(mbase + wid * 256 + lane * 4, (char*)Ms + wid * 1024);
  stage(0, 0);
  stage(1, 1);
  if (NT >= 4) {  // NT is even, so NT>2 means >=4
    stage(2, 2);
    asm volatile("s_waitcnt vmcnt(8)" ::: "memory");   // mask+t0 done
  } else {
    asm volatile("s_waitcnt vmcnt(4)" ::: "memory");
  }
  __builtin_amdgcn_sched_barrier(0);
  __builtin_amdgcn_s_barrier();

  for (int kt = 0; kt < NT; ++kt) {
    const int buf = kt & 3;
    const int k0 = kt * 32;
    if (kt + 3 < NT) stage((kt + 3) & 3, kt + 3);  // depth-3 prefetch

    // S^T = K·Q^T : s_acc[nt][j] = S[k = k0+nt*16+fq*4+j][q = qrow]
    f32x4 s_acc[2] = {};
#pragma unroll
    for (int kk = 0; kk < 2; ++kk)
#pragma unroll
      for (int nt = 0; nt < 2; ++nt) {
        int r = nt * 16 + fr;
        int byte = ((r << 7) + fq * 16 + kk * 64) ^ ((r & 7) << 4);
        bf16x8 kf = *(const bf16x8*)((const char*)Ks[buf] + byte);
        s_acc[nt] = MFMA16(kf, kk == 0 ? qf0 : qf1, s_acc[nt]);
      }

    // bias[q = wid*16+fr][k = nt*16+fq*4+{0..3}]
    float4 bv[2];
#pragma unroll
    for (int nt = 0; nt < 2; ++nt) {
      int byte = ((wid * 16 + fr) * 128 + nt * 64 + fq * 16) ^ ((fr & 7) << 4);
      bv[nt] = *(const float4*)((const char*)Bi[buf] + byte);
    }
    float4 mkv[2];
#pragma unroll
    for (int nt = 0; nt < 2; ++nt)
      mkv[nt] = *(const float4*)&Ms[k0 + nt * 16 + fq * 4];

    // softmax for this lane's q-row (8 k-values local)
    const bool diag = (kt >= NT - 2);
    float p[2][4];
    float mx = -3.0e38f;
#pragma unroll
    for (int nt = 0; nt < 2; ++nt)
#pragma unroll
      for (int j = 0; j < 4; ++j) {
        float mkj = (j == 0) ? mkv[nt].x : (j == 1) ? mkv[nt].y : (j == 2) ? mkv[nt].z : mkv[nt].w;
        float s = (s_acc[nt][j] + bv[nt][j]) * 0.03125f - (1.0f - mkj) * 3.125e8f;
        if (diag && (k0 + nt * 16 + fq * 4 + j) > qrow) s = -3.0e38f;
        p[nt][j] = s;
        mx = fmaxf(mx, s);
      }
    mx = fmaxf(mx, __shfl_xor(mx, 16));
    mx = fmaxf(mx, __shfl_xor(mx, 32));
    float mnew = fmaxf(m_run, mx);
    float corr = __expf(m_run - mnew);
    m_run = mnew;
    float rsum = 0.f;
#pragma unroll
    for (int nt = 0; nt < 2; ++nt)
#pragma unroll
      for (int j = 0; j < 4; ++j) {
        float e = __expf(p[nt][j] - mnew);
        p[nt][j] = e;
        rsum += e;
      }
    rsum += __shfl_xor(rsum, 16);
    rsum += __shfl_xor(rsum, 32);
    l_run = l_run * corr + rsum;
#pragma unroll
    for (int nt = 0; nt < 4; ++nt) o_acc[nt] *= corr;

    // P[q=fr][k] -> per-wave LDS (u32 packed), then B-frag read
#pragma unroll
    for (int nt = 0; nt < 2; ++nt) {
      unsigned int lo = (unsigned short)f2bf(p[nt][0]) |
                        ((unsigned int)(unsigned short)f2bf(p[nt][1]) << 16);
      unsigned int hi = (unsigned short)f2bf(p[nt][2]) |
                        ((unsigned int)(unsigned short)f2bf(p[nt][3]) << 16);
      *(unsigned int*)&Ps[wid][fr * 40 + nt * 16 + fq * 4] = lo;
      *(unsigned int*)&Ps[wid][fr * 40 + nt * 16 + fq * 4 + 2] = hi;
    }
    asm volatile("s_waitcnt lgkmcnt(0)" ::: "memory");
    bf16x8 pf = *(const bf16x8*)&Ps[wid][fr * 40 + fq * 8];  // B[col=q][k=fq*8..]

    // O += V^T · P : o_acc[nt2][j] = O[q = qrow][d = nt2*16+fq*4+j]
#pragma unroll
    for (int nt = 0; nt < 4; ++nt) {
      int r = nt * 16 + fr;
      int byte = ((r << 6) + fq * 16) ^ (((r ^ (r >> 2)) & 3) << 4);
      bf16x8 vf = *(const bf16x8*)((const char*)Vs[buf] + byte);
      o_acc[nt] = MFMA16(vf, pf, o_acc[nt]);
    }

    // end-of-tile sync: wait only for tile kt+1's loads (counted), then barrier
    if (kt + 1 < NT) {
      if (kt + 3 < NT)      asm volatile("s_waitcnt vmcnt(8)" ::: "memory");
      else if (kt + 2 < NT) asm volatile("s_waitcnt vmcnt(4)" ::: "memory");
      else                  asm volatile("s_waitcnt vmcnt(0)" ::: "memory");
      __builtin_amdgcn_sched_barrier(0);
      __builtin_amdgcn_s_barrier();
    }
  }

  // normalize + write merged-head bf16 [4096][1024]; short4 per nt
  float rl = 1.0f / l_run;
  size_t row = (size_t)(b * 1024 + q0 + wid * 16 + fr);
#pragma unroll
  for (int nt = 0; nt < 4; ++nt) {
    short4 sv;
    sv.x = f2bf(o_acc[nt][0] * rl);
    sv.y = f2bf(o_acc[nt][1] * rl);
    sv.z = f2bf(o_acc[nt][2] * rl);
    sv.w = f2bf(o_acc[nt][3] * rl);
    int col = (h & 15) * 64 + nt * 16 + fq * 4;
    *(short4*)&Aout[row * 1024 + col] = sv;
  }
}

// ---------------------------------------------------------------------------
extern "C" void kernel_launch(void* const* d_in, const int* in_sizes, int n_in,
                              void* d_out, int out_size, void* d_ws, size_t ws_size,
                              hipStream_t stream) {
  const float* query = (const float*)d_in[0];
  const float* key   = (const float*)d_in[1];
  const float* value = (const float*)d_in[2];
  const float* mask  = (const float*)d_in[3];
  const float* wts   = (const float*)d_in[4];
  const float* Wq    = (const float*)d_in[5];
  const float* bq    = (const float*)d_in[6];
  const float* Wk    = (const float*)d_in[7];
  const float* bk    = (const float*)d_in[8];
  const float* Wv    = (const float*)d_in[9];
  const float* bv    = (const float*)d_in[10];
  const float* Wo    = (const float*)d_in[11];
  const float* bo    = (const float*)d_in[12];

  char* ws = (char*)d_ws;
  const size_t MB = 1u << 20;
  short* qbf = (short*)(ws + 0);        // 8 MB  (reused as attn out)
  short* kbf = (short*)(ws + 8 * MB);   // 8 MB
  short* vbf = (short*)(ws + 16 * MB);  // 8 MB
  short* Wqb = (short*)(ws + 24 * MB);  // 2 MB
  short* Wkb = (short*)(ws + 26 * MB);
  short* Wvb = (short*)(ws + 28 * MB);
  short* Wob = (short*)(ws + 30 * MB);
  short* Qh  = (short*)(ws + 32 * MB);  // 8 MB [B,N,T,DH]
  short* Kh  = (short*)(ws + 40 * MB);  // 8 MB [B,N,T,DH]
  short* Vth = (short*)(ws + 48 * MB);  // 8 MB [B,N,DH,T]
  short* attnb = qbf;                   // alias: qbf dead after proj_qkv

  cvt_all<<<dim3(2048), dim3(256), 0, stream>>>(query, key, value, Wq, Wk, Wv, Wo,
                                                qbf, kbf, vbf, Wqb, Wkb, Wvb, Wob);
  proj_qkv<<<dim3(16, 16, 3), dim3(256), 0, stream>>>(qbf, kbf, vbf, Wqb, Wkb, Wvb,
                                                      bq, bk, bv, Qh, Kh, Vth);
  attn_kernel<<<dim3(16, 64), dim3(256), 0, stream>>>(Qh, Kh, Vth, wts, mask, attnb);
  gemm_out<<<dim3(16, 16), dim3(512), 0, stream>>>(attnb, Wob, bo, (float*)d_out);
}

// Round 8
// 183.675 us; speedup vs baseline: 1.0537x; 1.0537x over previous
//
#include <hip/hip_runtime.h>
#include <cstddef>

// ---------------------------------------------------------------------------
// MultiHead attention, B=4 T=1024 D=1024 N=16 DH=64, SCALE=32, causal + bias.
// Round 8: round-6 attn structure (KVBLK=64 dbuf, swapped QK^T) but bias goes
// to REGISTERS as float4 (depth-1 prefetch) instead of LDS: LDS 75->43 KB
// => 3 blocks/CU. Ps stride 88 (16B-aligned b128). proj/out/cvt unchanged.
// ---------------------------------------------------------------------------

typedef __attribute__((ext_vector_type(8))) short bf16x8;
typedef __attribute__((ext_vector_type(4))) float f32x4;

#define MFMA16(a, b, c) __builtin_amdgcn_mfma_f32_16x16x32_bf16(a, b, c, 0, 0, 0)

__device__ __forceinline__ short f2bf(float f) {
  union { float f; unsigned int i; } v; v.f = f;
  unsigned int r = v.i + 0x7FFFu + ((v.i >> 16) & 1u);  // RNE
  return (short)(r >> 16);
}

__device__ __forceinline__ void gload_lds16(const void* g, void* l) {
  __builtin_amdgcn_global_load_lds(
      (const __attribute__((address_space(1))) void*)g,
      (__attribute__((address_space(3))) void*)l, 16, 0, 0);
}

// ---------------------------------------------------------------------------
// Fused f32 -> bf16 conversion for all 7 tensors (one launch).
// ---------------------------------------------------------------------------
__global__ __launch_bounds__(256) void cvt_all(
    const float* __restrict__ q, const float* __restrict__ k, const float* __restrict__ v,
    const float* __restrict__ wq, const float* __restrict__ wk,
    const float* __restrict__ wv, const float* __restrict__ wo,
    short* __restrict__ qb, short* __restrict__ kb, short* __restrict__ vb,
    short* __restrict__ wqb, short* __restrict__ wkb,
    short* __restrict__ wvb, short* __restrict__ wob) {
  const int total = 16 * 1048576 / 4;  // vec4 count
  int stride = gridDim.x * blockDim.x;
  for (int i = blockIdx.x * blockDim.x + threadIdx.x; i < total; i += stride) {
    int e = i * 4;
    int chunk = e >> 20;
    const float* s;
    short* d;
    int off;
    if (chunk < 12) {
      if (chunk < 4)      { s = q; d = qb; }
      else if (chunk < 8) { s = k; d = kb; }
      else                { s = v; d = vb; }
      off = e & (4 * 1048576 - 1);
    } else {
      int w = chunk - 12;
      if (w == 0)      { s = wq; d = wqb; }
      else if (w == 1) { s = wk; d = wkb; }
      else if (w == 2) { s = wv; d = wvb; }
      else             { s = wo; d = wob; }
      off = e & (1048576 - 1);
    }
    float4 x = *(const float4*)(s + off);
    short4 o;
    o.x = f2bf(x.x); o.y = f2bf(x.y); o.z = f2bf(x.z); o.w = f2bf(x.w);
    *(short4*)(d + off) = o;
  }
}

// ---------------------------------------------------------------------------
// Fused Q/K/V projection: 256x64 tile, 4 waves stacked, BK=64 (round 3).
// ---------------------------------------------------------------------------
__global__ __launch_bounds__(256) void proj_qkv(
    const short* __restrict__ qA, const short* __restrict__ kA, const short* __restrict__ vA,
    const short* __restrict__ Wqb, const short* __restrict__ Wkb, const short* __restrict__ Wvb,
    const float* __restrict__ bq, const float* __restrict__ bk, const float* __restrict__ bv,
    short* __restrict__ Qh, short* __restrict__ Kh, short* __restrict__ Vth) {
  __shared__ short SMEM[256 * 64 + 64 * 64];  // As(32K) + Bs(8K); reused as Vt
  short* As = SMEM;
  short* Bs = SMEM + 256 * 64;

  const int m0 = blockIdx.x * 256;
  const int n0 = blockIdx.y * 64;
  const int z = blockIdx.z;

  const short *A, *W;
  const float* bias;
  if (z == 0)      { A = qA; W = Wqb; bias = bq; }
  else if (z == 1) { A = kA; W = Wkb; bias = bk; }
  else             { A = vA; W = Wvb; bias = bv; }

  const int tid = threadIdx.x;
  const int wid = tid >> 6, lane = tid & 63;
  const int fr = lane & 15, fq = lane >> 4;

  f32x4 acc[4][4] = {};

  for (int kt = 0; kt < 16; ++kt) {
#pragma unroll
    for (int c = 0; c < 8; ++c) {
      int pbase = c * 4096 + wid * 1024;
      int pb = pbase + lane * 16;
      int lb = pb ^ (((pb >> 7) & 7) << 4);
      int grow = lb >> 7, gcol = (lb & 127) >> 1;
      gload_lds16(A + (size_t)(m0 + grow) * 1024 + kt * 64 + gcol, (char*)As + pbase);
    }
#pragma unroll
    for (int c = 0; c < 2; ++c) {
      int pbase = c * 4096 + wid * 1024;
      int pb = pbase + lane * 16;
      int lb = pb ^ (((pb >> 7) & 7) << 4);
      int grow = lb >> 7, gcol = (lb & 127) >> 1;
      gload_lds16(W + (size_t)(n0 + grow) * 1024 + kt * 64 + gcol, (char*)Bs + pbase);
    }
    __syncthreads();
#pragma unroll
    for (int kk = 0; kk < 2; ++kk) {
      bf16x8 af[4], bg[4];
      int cb = (fq * 8 + kk * 32) * 2;
#pragma unroll
      for (int m = 0; m < 4; ++m) {
        int r = wid * 64 + m * 16 + fr;
        af[m] = *(const bf16x8*)((const char*)As + (((r << 7) + cb) ^ ((r & 7) << 4)));
      }
#pragma unroll
      for (int n = 0; n < 4; ++n) {
        int r = n * 16 + fr;
        bg[n] = *(const bf16x8*)((const char*)Bs + (((r << 7) + cb) ^ ((r & 7) << 4)));
      }
#pragma unroll
      for (int m = 0; m < 4; ++m)
#pragma unroll
        for (int n = 0; n < 4; ++n)
          acc[m][n] = MFMA16(af[m], bg[n], acc[m][n]);
    }
    __syncthreads();
  }

  if (z < 2) {
    short* dst = (z == 0) ? Qh : Kh;
#pragma unroll
    for (int m = 0; m < 4; ++m)
#pragma unroll
      for (int n = 0; n < 4; ++n) {
        int col = n0 + n * 16 + fr;
        float bval = bias[col];
        int row0 = m0 + wid * 64 + m * 16 + fq * 4;
        int hh = col >> 6, dh = col & 63;
#pragma unroll
        for (int j = 0; j < 4; ++j) {
          int row = row0 + j;
          int bb = row >> 10, t = row & 1023;
          dst[(((size_t)(bb * 16 + hh)) * 1024 + t) * 64 + dh] = f2bf(acc[m][n][j] + bval);
        }
      }
  } else {
    short* Vt = SMEM;  // [64][264] shorts
#pragma unroll
    for (int m = 0; m < 4; ++m)
#pragma unroll
      for (int n = 0; n < 4; ++n) {
        int coll = n * 16 + fr;
        float bval = bias[n0 + coll];
        int rowl0 = wid * 64 + m * 16 + fq * 4;
#pragma unroll
        for (int j = 0; j < 4; ++j)
          Vt[coll * 264 + rowl0 + j] = f2bf(acc[m][n][j] + bval);
      }
    __syncthreads();
    const int bb = m0 >> 10, t0 = m0 & 1023;
#pragma unroll
    for (int it = 0; it < 8; ++it) {
      int qq = tid + it * 256;
      int rowl = qq >> 5, seg = qq & 31;
      bf16x8 vv = *(const bf16x8*)&Vt[rowl * 264 + seg * 8];
      int cg = n0 + rowl, hh = cg >> 6, dh = cg & 63;
      *(bf16x8*)&Vth[(((size_t)(bb * 16 + hh)) * 64 + dh) * 1024 + t0 + seg * 8] = vv;
    }
  }
}

// ---------------------------------------------------------------------------
// Output projection: 512 thr / 8 waves, 256x64 tile (round 3).
// ---------------------------------------------------------------------------
__global__ __launch_bounds__(512) void gemm_out(const short* __restrict__ A,
                                                const short* __restrict__ W,
                                                const float* __restrict__ bias,
                                                float* __restrict__ C) {
  __shared__ short As[256 * 64];
  __shared__ short Bs[64 * 64];
  const int m0 = blockIdx.x * 256;
  const int n0 = blockIdx.y * 64;

  const int tid = threadIdx.x;
  const int wid = tid >> 6, lane = tid & 63;
  const int fr = lane & 15, fq = lane >> 4;

  f32x4 acc[2][4] = {};

  for (int kt = 0; kt < 16; ++kt) {
#pragma unroll
    for (int c = 0; c < 4; ++c) {
      int pbase = c * 8192 + wid * 1024;
      int pb = pbase + lane * 16;
      int lb = pb ^ (((pb >> 7) & 7) << 4);
      int grow = lb >> 7, gcol = (lb & 127) >> 1;
      gload_lds16(A + (size_t)(m0 + grow) * 1024 + kt * 64 + gcol, (char*)As + pbase);
    }
    {
      int pbase = wid * 1024;
      int pb = pbase + lane * 16;
      int lb = pb ^ (((pb >> 7) & 7) << 4);
      int grow = lb >> 7, gcol = (lb & 127) >> 1;
      gload_lds16(W + (size_t)(n0 + grow) * 1024 + kt * 64 + gcol, (char*)Bs + pbase);
    }
    __syncthreads();
#pragma unroll
    for (int kk = 0; kk < 2; ++kk) {
      bf16x8 af[2], bg[4];
      int cb = (fq * 8 + kk * 32) * 2;
#pragma unroll
      for (int m = 0; m < 2; ++m) {
        int r = wid * 32 + m * 16 + fr;
        af[m] = *(const bf16x8*)((const char*)As + (((r << 7) + cb) ^ ((r & 7) << 4)));
      }
#pragma unroll
      for (int n = 0; n < 4; ++n) {
        int r = n * 16 + fr;
        bg[n] = *(const bf16x8*)((const char*)Bs + (((r << 7) + cb) ^ ((r & 7) << 4)));
      }
#pragma unroll
      for (int m = 0; m < 2; ++m)
#pragma unroll
        for (int n = 0; n < 4; ++n)
          acc[m][n] = MFMA16(af[m], bg[n], acc[m][n]);
    }
    __syncthreads();
  }

#pragma unroll
  for (int m = 0; m < 2; ++m)
#pragma unroll
    for (int n = 0; n < 4; ++n) {
      int col = n0 + n * 16 + fr;
      float bval = bias[col];
      int row0 = m0 + wid * 32 + m * 16 + fq * 4;
#pragma unroll
      for (int j = 0; j < 4; ++j)
        C[(size_t)(row0 + j) * 1024 + col] = acc[m][n][j] + bval;
    }
}

// ---------------------------------------------------------------------------
// Flash attention: grid (16 q-tiles, 64 heads), 256 thr (4 waves), QBLK=64,
// KVBLK=64 double-buffered K/V in LDS. Swapped QK^T (lane owns one q-row).
// Bias in REGISTERS: 4x float4/lane per tile, depth-1 prefetch at iter top,
// consumed next iter (full compute phase + barrier of slack). LDS 43 KB ->
// 3 blocks/CU.
// ---------------------------------------------------------------------------
__global__ __launch_bounds__(256) void attn_kernel(
    const short* __restrict__ Qh, const short* __restrict__ Kh,
    const short* __restrict__ Vth, const float* __restrict__ Wb,
    const float* __restrict__ mask, short* __restrict__ Aout) {
  __shared__ short Ks[2][64 * 64];    // 8 KB x2, 128B rows, ^((r&7)<<4)
  __shared__ short Vs[2][64 * 64];    // 8 KB x2 (V^T [dh][t])
  __shared__ short Ps[4][16 * 88];    // per-wave P, stride 88 (16B-aligned b128)

  const int tid = threadIdx.x;
  const int wid = tid >> 6, lane = tid & 63;
  const int fr = lane & 15, fq = lane >> 4;
  const int h = blockIdx.y, b = h >> 4;
  const int qi = (int)gridDim.x - 1 - (int)blockIdx.x;  // heavy tiles first
  const int q0 = qi * 64;
  const int qrow = q0 + wid * 16 + fr;  // this lane's q-row

  // Q fragment (B-operand): Q[qrow][fq*8 + {0..7}] (+32 for kk=1)
  const short* qbase = Qh + ((size_t)h * 1024 + qrow) * 64 + fq * 8;
  bf16x8 qf0 = *(const bf16x8*)qbase;
  bf16x8 qf1 = *(const bf16x8*)(qbase + 32);

  const short* Kbase = Kh + (size_t)h * 1024 * 64;
  const short* Vbase = Vth + (size_t)h * 64 * 1024;
  const float* wrow = Wb + (size_t)h * 1024 * 1024 + (size_t)qrow * 1024;
  const f32x4* mask4 = (const f32x4*)(mask + b * 1024);

  auto stage = [&](int buf, int k0) {
    // K tile [t][dh], V^T tile [dh][t]; 128B rows, swz row&7
#pragma unroll
    for (int c = 0; c < 2; ++c) {
      int pbase = c * 4096 + wid * 1024;
      int pb = pbase + lane * 16;
      int lb = pb ^ (((pb >> 7) & 7) << 4);
      int grow = lb >> 7, gcol = (lb & 127) >> 1;
      gload_lds16(Kbase + (size_t)(k0 + grow) * 64 + gcol, (char*)Ks[buf] + pbase);
      gload_lds16(Vbase + (size_t)grow * 1024 + k0 + gcol, (char*)Vs[buf] + pbase);
    }
  };

  // bias[qrow][k0 + nt*16 + fq*4 + {0..3}] : one float4 per nt, coalesced
  auto load_bias = [&](f32x4 (&bv)[4], int k0) {
#pragma unroll
    for (int nt = 0; nt < 4; ++nt)
      bv[nt] = *(const f32x4*)(wrow + k0 + nt * 16 + fq * 4);
  };

  f32x4 o_acc[4] = {};
  float m_run = -3.0e38f, l_run = 0.f;
  f32x4 bias_cur[4], bias_nxt[4];

  stage(0, 0);
  load_bias(bias_cur, 0);
  __syncthreads();
  int cur = 0;

  for (int kt = 0; kt <= qi; ++kt) {
    const int k0 = kt * 64;
    if (kt < qi) {                       // prefetch next tile (K/V LDS + bias regs)
      stage(cur ^ 1, k0 + 64);
      load_bias(bias_nxt, k0 + 64);
    }
    const bool diag = (kt == qi);

    // mask values per k = nt*16 + fq*4 + {0..3}
    f32x4 mkv[4];
#pragma unroll
    for (int nt = 0; nt < 4; ++nt) mkv[nt] = mask4[(k0 >> 2) + nt * 4 + fq];

    // S^T = K·Q^T : s_acc[nt][j] = S[k = k0+nt*16+fq*4+j][q = qrow]
    f32x4 s_acc[4] = {};
#pragma unroll
    for (int kk = 0; kk < 2; ++kk)
#pragma unroll
      for (int nt = 0; nt < 4; ++nt) {
        int r = nt * 16 + fr;
        int cb = fq * 16 + kk * 64;
        bf16x8 kf = *(const bf16x8*)((const char*)Ks[cur] + (((r << 7) + cb) ^ ((r & 7) << 4)));
        s_acc[nt] = MFMA16(kf, kk == 0 ? qf0 : qf1, s_acc[nt]);
      }

    // softmax for this lane's q-row (all 16 k-values local)
    float p[4][4];
    float mx = -3.0e38f;
#pragma unroll
    for (int nt = 0; nt < 4; ++nt)
#pragma unroll
      for (int j = 0; j < 4; ++j) {
        float s = (s_acc[nt][j] + bias_cur[nt][j]) * 0.03125f
                  - (1.0f - mkv[nt][j]) * 3.125e8f;
        if (diag && (nt * 16 + fq * 4 + j) > (wid * 16 + fr)) s = -3.0e38f;
        p[nt][j] = s;
        mx = fmaxf(mx, s);
      }
    mx = fmaxf(mx, __shfl_xor(mx, 16));
    mx = fmaxf(mx, __shfl_xor(mx, 32));
    float mnew = fmaxf(m_run, mx);
    float corr = __expf(m_run - mnew);
    m_run = mnew;
    float rsum = 0.f;
#pragma unroll
    for (int nt = 0; nt < 4; ++nt)
#pragma unroll
      for (int j = 0; j < 4; ++j) {
        float e = __expf(p[nt][j] - mnew);
        p[nt][j] = e;
        rsum += e;
      }
    rsum += __shfl_xor(rsum, 16);
    rsum += __shfl_xor(rsum, 32);
    l_run = l_run * corr + rsum;
#pragma unroll
    for (int nt = 0; nt < 4; ++nt) o_acc[nt] *= corr;

    // P[q = fr][k = nt*16+fq*4+{0..3}] -> per-wave LDS (packed u32 writes)
#pragma unroll
    for (int nt = 0; nt < 4; ++nt) {
      unsigned int lo = (unsigned short)f2bf(p[nt][0]) |
                        ((unsigned int)(unsigned short)f2bf(p[nt][1]) << 16);
      unsigned int hi = (unsigned short)f2bf(p[nt][2]) |
                        ((unsigned int)(unsigned short)f2bf(p[nt][3]) << 16);
      *(unsigned int*)&Ps[wid][fr * 88 + nt * 16 + fq * 4] = lo;
      *(unsigned int*)&Ps[wid][fr * 88 + nt * 16 + fq * 4 + 2] = hi;
    }
    asm volatile("s_waitcnt lgkmcnt(0)" ::: "memory");
    bf16x8 pf0 = *(const bf16x8*)&Ps[wid][fr * 88 + fq * 8];        // B[col=q][k]
    bf16x8 pf1 = *(const bf16x8*)&Ps[wid][fr * 88 + fq * 8 + 32];

    // O^T = V^T · P : o_acc[nt][j] = O[q = qrow][d = nt*16+fq*4+j]
#pragma unroll
    for (int kk = 0; kk < 2; ++kk)
#pragma unroll
      for (int nt = 0; nt < 4; ++nt) {
        int r = nt * 16 + fr;
        int cb = fq * 16 + kk * 64;
        bf16x8 vf = *(const bf16x8*)((const char*)Vs[cur] + (((r << 7) + cb) ^ ((r & 7) << 4)));
        o_acc[nt] = MFMA16(vf, kk == 0 ? pf0 : pf1, o_acc[nt]);
      }

    __syncthreads();  // all waves done with [cur]; prefetch into [cur^1] drained
    if (kt < qi) {
#pragma unroll
      for (int nt = 0; nt < 4; ++nt) bias_cur[nt] = bias_nxt[nt];
    }
    cur ^= 1;
  }

  // normalize + write merged-head bf16 [4096][1024]; short4 per nt
  float rl = 1.0f / l_run;
  size_t row = (size_t)(b * 1024 + q0 + wid * 16 + fr);
#pragma unroll
  for (int nt = 0; nt < 4; ++nt) {
    short4 sv;
    sv.x = f2bf(o_acc[nt][0] * rl);
    sv.y = f2bf(o_acc[nt][1] * rl);
    sv.z = f2bf(o_acc[nt][2] * rl);
    sv.w = f2bf(o_acc[nt][3] * rl);
    int col = (h & 15) * 64 + nt * 16 + fq * 4;
    *(short4*)&Aout[row * 1024 + col] = sv;
  }
}

// ---------------------------------------------------------------------------
extern "C" void kernel_launch(void* const* d_in, const int* in_sizes, int n_in,
                              void* d_out, int out_size, void* d_ws, size_t ws_size,
                              hipStream_t stream) {
  const float* query = (const float*)d_in[0];
  const float* key   = (const float*)d_in[1];
  const float* value = (const float*)d_in[2];
  const float* mask  = (const float*)d_in[3];
  const float* wts   = (const float*)d_in[4];
  const float* Wq    = (const float*)d_in[5];
  const float* bq    = (const float*)d_in[6];
  const float* Wk    = (const float*)d_in[7];
  const float* bk    = (const float*)d_in[8];
  const float* Wv    = (const float*)d_in[9];
  const float* bv    = (const float*)d_in[10];
  const float* Wo    = (const float*)d_in[11];
  const float* bo    = (const float*)d_in[12];

  char* ws = (char*)d_ws;
  const size_t MB = 1u << 20;
  short* qbf = (short*)(ws + 0);        // 8 MB  (reused as attn out)
  short* kbf = (short*)(ws + 8 * MB);   // 8 MB
  short* vbf = (short*)(ws + 16 * MB);  // 8 MB
  short* Wqb = (short*)(ws + 24 * MB);  // 2 MB
  short* Wkb = (short*)(ws + 26 * MB);
  short* Wvb = (short*)(ws + 28 * MB);
  short* Wob = (short*)(ws + 30 * MB);
  short* Qh  = (short*)(ws + 32 * MB);  // 8 MB [B,N,T,DH]
  short* Kh  = (short*)(ws + 40 * MB);  // 8 MB [B,N,T,DH]
  short* Vth = (short*)(ws + 48 * MB);  // 8 MB [B,N,DH,T]
  short* attnb = qbf;                   // alias: qbf dead after proj_qkv

  cvt_all<<<dim3(2048), dim3(256), 0, stream>>>(query, key, value, Wq, Wk, Wv, Wo,
                                                qbf, kbf, vbf, Wqb, Wkb, Wvb, Wob);
  proj_qkv<<<dim3(16, 16, 3), dim3(256), 0, stream>>>(qbf, kbf, vbf, Wqb, Wkb, Wvb,
                                                      bq, bk, bv, Qh, Kh, Vth);
  attn_kernel<<<dim3(16, 64), dim3(256), 0, stream>>>(Qh, Kh, Vth, wts, mask, attnb);
  gemm_out<<<dim3(16, 16), dim3(512), 0, stream>>>(attnb, Wob, bo, (float*)d_out);
}